// Round 4
// baseline (219.235 us; speedup 1.0000x reference)
//
#include <hip/hip_runtime.h>
#include <hip/hip_bf16.h>
#include <math.h>

#define T_TOK 3072
#define HID   1024
#define NH    16
#define HD    64
#define KVSPLIT 4
#define KVCHUNK (T_TOK / KVSPLIT)   // 768
#define LOG2E 1.4426950408889634f

typedef __attribute__((ext_vector_type(8))) short bf16x8;
typedef __attribute__((ext_vector_type(4))) short bf16x4;
typedef __attribute__((ext_vector_type(4))) float f32x4;

static __device__ __forceinline__ unsigned short f2bf(float x) {
  __hip_bfloat16 h = __float2bfloat16(x);
  return __builtin_bit_cast(unsigned short, h);
}

// swizzled LDS short-index for a [rows][64 bf16] tile, row stride 128B.
// byte address = row*128 + (col_bytes ^ ((row&7)<<4)); identical on write & read.
static __device__ __forceinline__ int swz(int row, int cb) {
  return row * 64 + ((cb ^ ((row & 7) << 4)) >> 1);
}

// ---------------- elementwise fp32 -> bf16 ----------------
__global__ __launch_bounds__(256) void cvt_bf16(const float* __restrict__ in,
                                                unsigned short* __restrict__ out, int n) {
  int i = (blockIdx.x * 256 + threadIdx.x) * 4;
  if (i < n) {
    float4 v = *(const float4*)(in + i);
    ushort4 o;
    o.x = f2bf(v.x); o.y = f2bf(v.y); o.z = f2bf(v.z); o.w = f2bf(v.w);
    *(ushort4*)(out + i) = o;
  }
}

// ---------------- transpose + convert: out[C][R] = bf16(in[R][C]) ----------------
__global__ __launch_bounds__(256) void transpose_cvt(const float* __restrict__ in,
                                                     unsigned short* __restrict__ out,
                                                     int R, int C) {
  __shared__ float tile[32][33];
  int c0 = blockIdx.x * 32, r0 = blockIdx.y * 32;
  int tx = threadIdx.x & 31, ty = threadIdx.x >> 5; // ty 0..7
  #pragma unroll
  for (int i = 0; i < 32; i += 8)
    tile[ty + i][tx] = in[(size_t)(r0 + ty + i) * C + c0 + tx];
  __syncthreads();
  #pragma unroll
  for (int i = 0; i < 32; i += 8)
    out[(size_t)(c0 + ty + i) * R + r0 + tx] = f2bf(tile[tx][ty + i]);
}

// ---------------- RoPE cos/sin tables [T][32] ----------------
__global__ __launch_bounds__(256) void rope_table(const int* __restrict__ pos,
                                                  float* __restrict__ ctab,
                                                  float* __restrict__ stab) {
  int i = blockIdx.x * 256 + threadIdx.x;  // T*32
  int t = i >> 5, j = i & 31;
  float inv = expf(-(float)j * 0.28782313662425572f);  // 10000^(-j/32)
  float f = (float)pos[t] * inv;
  ctab[i] = cosf(f);
  stab[i] = sinf(f);
}

// ---------------- RoPE apply + split Q,K to [H][T][D] bf16 ----------------
// Q is pre-scaled by 0.125 * log2(e) so softmax runs in exp2 domain.
__global__ __launch_bounds__(256) void rope_split(const float* __restrict__ QKV,
                                                  const float* __restrict__ ctab,
                                                  const float* __restrict__ stab,
                                                  unsigned short* __restrict__ Qh,
                                                  unsigned short* __restrict__ Kh) {
  const float QSCL = 0.18033688011112042f;  // 0.125 * log2e
  int i = blockIdx.x * 256 + threadIdx.x;  // T*NH*32
  int j = i & 31, h = (i >> 5) & 15, t = i >> 9;
  size_t base = (size_t)t * (3 * HID) + h * HD + j;
  float c = ctab[t * 32 + j], s = stab[t * 32 + j];
  float q1 = QKV[base], q2 = QKV[base + 32];
  float k1 = QKV[base + HID], k2 = QKV[base + HID + 32];
  size_t ob = ((size_t)h * T_TOK + t) * HD + j;
  Qh[ob]      = f2bf((q1 * c - q2 * s) * QSCL);
  Qh[ob + 32] = f2bf((q2 * c + q1 * s) * QSCL);
  Kh[ob]      = f2bf(k1 * c - k2 * s);
  Kh[ob + 32] = f2bf(k2 * c + k1 * s);
}

// ---------------- V: QKV[:,2048+h*64+d] -> Vt[H][D][T] bf16 ----------------
__global__ __launch_bounds__(256) void v_transpose(const float* __restrict__ QKV,
                                                   unsigned short* __restrict__ Vt) {
  int h = blockIdx.y;
  int t0 = blockIdx.x * 64;
  __shared__ unsigned short lds[64][72];
  int tx = threadIdx.x & 63, ty = threadIdx.x >> 6;  // ty 0..3
  #pragma unroll
  for (int i = 0; i < 16; ++i) {
    int t = ty * 16 + i;
    lds[tx][t] = f2bf(QKV[(size_t)(t0 + t) * (3 * HID) + 2 * HID + h * HD + tx]);
  }
  __syncthreads();
  #pragma unroll
  for (int i = 0; i < 16; ++i) {
    int d = ty * 16 + i;
    Vt[((size_t)h * HD + d) * T_TOK + t0 + tx] = lds[d][tx];
  }
}

// ---------------- GEMM: C[M,N] f32 = A[M,K] bf16 x Bt[N,K] bf16 ----------------
__global__ __launch_bounds__(256) void gemm_bt(const unsigned short* __restrict__ A,
                                               const unsigned short* __restrict__ Bt,
                                               float* __restrict__ C,
                                               int M, int N, int K) {
  __shared__ unsigned short As[128 * 64];
  __shared__ unsigned short Bs[128 * 64];
  const int lane = threadIdx.x & 63;
  const int wv = threadIdx.x >> 6;
  const int wm = wv >> 1, wn = wv & 1;
  const int r = lane & 15, hi = lane >> 4;
  const int m0 = blockIdx.y * 128, n0 = blockIdx.x * 128;
  f32x4 acc[4][4] = {};
  for (int kt = 0; kt < K; kt += 64) {
    __syncthreads();
    #pragma unroll
    for (int i = 0; i < 4; ++i) {
      int o = (wv * 4 + i) * 1024 + lane * 16;  // byte offset into 16KB tile
      int row = o >> 7;                          // 128B per row (64 bf16)
      int col = (o & 127) >> 1;
      const unsigned short* ga = A + (size_t)(m0 + row) * K + kt + col;
      __builtin_amdgcn_global_load_lds(
          (const __attribute__((address_space(1))) unsigned int*)ga,
          (__attribute__((address_space(3))) unsigned int*)((char*)As + (wv * 4 + i) * 1024),
          16, 0, 0);
      const unsigned short* gb = Bt + (size_t)(n0 + row) * K + kt + col;
      __builtin_amdgcn_global_load_lds(
          (const __attribute__((address_space(1))) unsigned int*)gb,
          (__attribute__((address_space(3))) unsigned int*)((char*)Bs + (wv * 4 + i) * 1024),
          16, 0, 0);
    }
    __syncthreads();
    #pragma unroll
    for (int kk = 0; kk < 2; ++kk) {
      bf16x8 a[4], b[4];
      #pragma unroll
      for (int tm = 0; tm < 4; ++tm)
        a[tm] = *(const bf16x8*)&As[(wm * 64 + tm * 16 + r) * 64 + kk * 32 + hi * 8];
      #pragma unroll
      for (int tn = 0; tn < 4; ++tn)
        b[tn] = *(const bf16x8*)&Bs[(wn * 64 + tn * 16 + r) * 64 + kk * 32 + hi * 8];
      #pragma unroll
      for (int tm = 0; tm < 4; ++tm)
        #pragma unroll
        for (int tn = 0; tn < 4; ++tn)
          acc[tm][tn] = __builtin_amdgcn_mfma_f32_16x16x32_bf16(a[tm], b[tn], acc[tm][tn], 0, 0, 0);
    }
  }
  #pragma unroll
  for (int tm = 0; tm < 4; ++tm)
    #pragma unroll
    for (int tn = 0; tn < 4; ++tn) {
      int colg = n0 + wn * 64 + tn * 16 + r;
      int rowg = m0 + wm * 64 + tm * 16 + hi * 4;
      float* cp = C + (size_t)rowg * N + colg;
      #pragma unroll
      for (int j = 0; j < 4; ++j) cp[(size_t)j * N] = acc[tm][tn][j];
    }
}

// ---------------- flash attention, KV-split, 2-phase pipelined ----------------
// grid: 1D T/64 * NH * KVSPLIT, XCD-remapped. block 256 = 4 waves x 16 q-rows.
// Double-buffered K/V LDS: STAGE(buf^1, t+1) issues BEFORE compute(buf[cur]),
// so the compiler's vmcnt(0)-before-barrier drain lands after ~full-tile compute.
__global__ __launch_bounds__(256) void flash_attn(const unsigned short* __restrict__ Qh,
                                                  const unsigned short* __restrict__ Kh,
                                                  const unsigned short* __restrict__ Vt,
                                                  const float* __restrict__ mask,
                                                  float* __restrict__ Op,
                                                  float* __restrict__ Mp,
                                                  float* __restrict__ Lp) {
  const int NBLK = (T_TOK / 64) * NH * KVSPLIT;     // 3072, divisible by 8
  int id = blockIdx.x;
  int sid = (id & 7) * (NBLK / 8) + (id >> 3);      // bijective XCD chunking
  const int h = sid & 15;
  int t2 = sid >> 4;                                 // 0..191
  const int qx = t2 % (T_TOK / 64);
  const int z  = t2 / (T_TOK / 64);
  const int q0 = qx * 64;
  const int kv0 = z * KVCHUNK;
  const int NT = KVCHUNK / 64;                       // 12

  __shared__ unsigned short Ks[2][64 * 64];
  __shared__ unsigned short Vs[2][64 * 64];
  const int lane = threadIdx.x & 63, wv = threadIdx.x >> 6;
  const int r = lane & 15, hi = lane >> 4;
  const int qrow = q0 + wv * 16 + r;
  const bf16x8 qf0 = *(const bf16x8*)(Qh + ((size_t)h * T_TOK + qrow) * HD + hi * 8);
  const bf16x8 qf1 = *(const bf16x8*)(Qh + ((size_t)h * T_TOK + qrow) * HD + 32 + hi * 8);
  f32x4 acc_o[4] = {};
  float m = -INFINITY, l = 0.f;

  // global_load_lds staging: LDS written linearly (base + lane*16), source
  // pre-swizzled so LDS[row][cb] = src[row][cb ^ ((row&7)<<4)].
  const int ldrow = lane >> 3;                         // == dest row & 7
  const int colS  = ((lane & 7) * 16) ^ (ldrow << 4);  // source byte col
  const unsigned short* kga = Kh + ((size_t)h * T_TOK + wv * 16 + ldrow) * HD + (colS >> 1);
  const unsigned short* vga = Vt + ((size_t)h * HD + wv * 16 + ldrow) * T_TOK + (colS >> 1);
  char* ksd = (char*)&Ks[0][0] + wv * 2048;
  char* vsd = (char*)&Vs[0][0] + wv * 2048;
  const float* mrow = mask + (size_t)qrow * T_TOK;

  auto stage = [&](int buf, int s0) {
    __builtin_amdgcn_global_load_lds(
        (const __attribute__((address_space(1))) unsigned int*)(kga + (size_t)s0 * HD),
        (__attribute__((address_space(3))) unsigned int*)(ksd + buf * 8192), 16, 0, 0);
    __builtin_amdgcn_global_load_lds(
        (const __attribute__((address_space(1))) unsigned int*)(kga + (size_t)s0 * HD + 8 * HD),
        (__attribute__((address_space(3))) unsigned int*)(ksd + buf * 8192 + 1024), 16, 0, 0);
    __builtin_amdgcn_global_load_lds(
        (const __attribute__((address_space(1))) unsigned int*)(vga + s0),
        (__attribute__((address_space(3))) unsigned int*)(vsd + buf * 8192), 16, 0, 0);
    __builtin_amdgcn_global_load_lds(
        (const __attribute__((address_space(1))) unsigned int*)(vga + s0 + 8 * T_TOK),
        (__attribute__((address_space(3))) unsigned int*)(vsd + buf * 8192 + 1024), 16, 0, 0);
  };

  // prologue: stage tile 0 + its mask
  stage(0, kv0);
  float4 mk[4], mkn[4];
  #pragma unroll
  for (int b = 0; b < 4; ++b) mk[b] = *(const float4*)(mrow + kv0 + b * 16 + hi * 4);
  __syncthreads();  // vmcnt(0) drain: tile 0 ready

  int cur = 0;
  for (int it = 0; it < NT; ++it) {
    const int s0 = kv0 + it * 64;
    // issue next tile's staging + mask prefetch (hidden under this tile's compute)
    if (it + 1 < NT) {
      stage(cur ^ 1, s0 + 64);
      #pragma unroll
      for (int b = 0; b < 4; ++b) mkn[b] = *(const float4*)(mrow + s0 + 64 + b * 16 + hi * 4);
    }

    // QK^T -> S^T[kv,q]; Q pre-scaled by 0.125*log2e, mask folded via fma
    float sv[16];
    __builtin_amdgcn_s_setprio(1);
    #pragma unroll
    for (int b = 0; b < 4; ++b) {
      bf16x8 kf0 = *(const bf16x8*)&Ks[cur][swz(b * 16 + r, hi * 16)];
      bf16x8 kf1 = *(const bf16x8*)&Ks[cur][swz(b * 16 + r, 64 + hi * 16)];
      f32x4 zf = {};
      zf = __builtin_amdgcn_mfma_f32_16x16x32_bf16(kf0, qf0, zf, 0, 0, 0);
      zf = __builtin_amdgcn_mfma_f32_16x16x32_bf16(kf1, qf1, zf, 0, 0, 0);
      sv[b * 4 + 0] = fmaf(mk[b].x, LOG2E, zf[0]);
      sv[b * 4 + 1] = fmaf(mk[b].y, LOG2E, zf[1]);
      sv[b * 4 + 2] = fmaf(mk[b].z, LOG2E, zf[2]);
      sv[b * 4 + 3] = fmaf(mk[b].w, LOG2E, zf[3]);
    }
    __builtin_amdgcn_s_setprio(0);

    // row max via max3 tree + 4-lane group reduce
    float t0 = fmaxf(fmaxf(sv[0], sv[1]), sv[2]);
    float t1 = fmaxf(fmaxf(sv[3], sv[4]), sv[5]);
    float t2m = fmaxf(fmaxf(sv[6], sv[7]), sv[8]);
    float t3 = fmaxf(fmaxf(sv[9], sv[10]), sv[11]);
    float t4 = fmaxf(fmaxf(sv[12], sv[13]), sv[14]);
    float pmax = fmaxf(fmaxf(fmaxf(t0, t1), t2m), fmaxf(fmaxf(t3, t4), sv[15]));
    pmax = fmaxf(pmax, __shfl_xor(pmax, 16));
    pmax = fmaxf(pmax, __shfl_xor(pmax, 32));

    // defer-max: only rescale when the running max grew by > 8 (log2 units)
    if (__any(pmax > m + 8.f)) {
      float mnew = fmaxf(m, pmax);
      float sc = __builtin_amdgcn_exp2f(m - mnew);
      m = mnew;
      l *= sc;
      float sc0 = __shfl(sc, hi * 4 + 0);
      float sc1 = __shfl(sc, hi * 4 + 1);
      float sc2 = __shfl(sc, hi * 4 + 2);
      float sc3 = __shfl(sc, hi * 4 + 3);
      #pragma unroll
      for (int d = 0; d < 4; ++d) {
        acc_o[d][0] *= sc0; acc_o[d][1] *= sc1;
        acc_o[d][2] *= sc2; acc_o[d][3] *= sc3;
      }
    }

    // P = exp2(sv - m), packed straight into K=16 A-fragments (no LDS roundtrip)
    float ps = 0.f;
    bf16x4 pa[4];
    #pragma unroll
    for (int b = 0; b < 4; ++b) {
      bf16x4 t;
      #pragma unroll
      for (int j = 0; j < 4; ++j) {
        float p = __builtin_amdgcn_exp2f(sv[b * 4 + j] - m);
        ps += p;
        t[j] = (short)f2bf(p);
      }
      pa[b] = t;
    }
    ps += __shfl_xor(ps, 16);
    ps += __shfl_xor(ps, 32);
    l += ps;

    // PV: O[q,d] += P[q,kv] * V[kv,d] via 16 x mfma_16x16x16 (A = pa, in regs)
    __builtin_amdgcn_s_setprio(1);
    #pragma unroll
    for (int d = 0; d < 4; ++d)
      #pragma unroll
      for (int b = 0; b < 4; ++b) {
        bf16x4 vf = *(const bf16x4*)&Vs[cur][swz(d * 16 + r, b * 32 + hi * 8)];
        acc_o[d] = __builtin_amdgcn_mfma_f32_16x16x16bf16_1k(pa[b], vf, acc_o[d], 0, 0, 0);
      }
    __builtin_amdgcn_s_setprio(0);

    __syncthreads();  // vmcnt(0) drain (next tile's loads have had full compute to land)
    #pragma unroll
    for (int b = 0; b < 4; ++b) mk[b] = mkn[b];
    cur ^= 1;
  }

  // epilogue: write unnormalized partials + (m,l) (m in log2 domain)
  #pragma unroll
  for (int d = 0; d < 4; ++d)
    #pragma unroll
    for (int j = 0; j < 4; ++j) {
      int trow = q0 + wv * 16 + hi * 4 + j;
      Op[(((size_t)z * T_TOK + trow) * NH + h) * HD + d * 16 + r] = acc_o[d][j];
    }
  if (hi == 0) {
    size_t mi = ((size_t)z * T_TOK + qrow) * NH + h;
    Mp[mi] = m;
    Lp[mi] = l;
  }
}

// ---------------- combine KV-split partials (log2-domain maxes) ----------------
__global__ __launch_bounds__(256) void combine(const float* __restrict__ Op,
                                               const float* __restrict__ Mp,
                                               const float* __restrict__ Lp,
                                               unsigned short* __restrict__ Ob) {
  int idx = blockIdx.x * 256 + threadIdx.x;  // T*256 total (4 floats each)
  int t = idx >> 8;
  int q4 = (idx & 255) * 4;  // within [HID): h*64 + d
  int h = q4 >> 6, d = q4 & 63;
  float mz[KVSPLIT], lz[KVSPLIT];
  float ms = -INFINITY;
  #pragma unroll
  for (int zz = 0; zz < KVSPLIT; ++zz) {
    size_t mi = ((size_t)zz * T_TOK + t) * NH + h;
    mz[zz] = Mp[mi];
    lz[zz] = Lp[mi];
    ms = fmaxf(ms, mz[zz]);
  }
  float lsum = 0.f;
  float w[KVSPLIT];
  #pragma unroll
  for (int zz = 0; zz < KVSPLIT; ++zz) {
    w[zz] = __builtin_amdgcn_exp2f(mz[zz] - ms);
    lsum += lz[zz] * w[zz];
  }
  float4 o = {0.f, 0.f, 0.f, 0.f};
  #pragma unroll
  for (int zz = 0; zz < KVSPLIT; ++zz) {
    float4 p = *(const float4*)(Op + (((size_t)zz * T_TOK + t) * NH + h) * HD + d);
    o.x += p.x * w[zz]; o.y += p.y * w[zz];
    o.z += p.z * w[zz]; o.w += p.w * w[zz];
  }
  float inv = 1.f / lsum;
  ushort4 ob;
  ob.x = f2bf(o.x * inv); ob.y = f2bf(o.y * inv);
  ob.z = f2bf(o.z * inv); ob.w = f2bf(o.w * inv);
  *(ushort4*)(Ob + (size_t)t * HID + q4) = ob;
}

extern "C" void kernel_launch(void* const* d_in, const int* in_sizes, int n_in,
                              void* d_out, int out_size, void* d_ws, size_t ws_size,
                              hipStream_t stream) {
  const float* X    = (const float*)d_in[0];
  const float* Wqkv = (const float*)d_in[1];
  const float* Wo   = (const float*)d_in[2];
  const float* mask = (const float*)d_in[3];
  const int*   pos  = (const int*)d_in[4];
  float* out = (float*)d_out;

  char* ws = (char*)d_ws;
  size_t off = 0;
  auto alloc = [&](size_t bytes) {
    char* p = ws + off;
    off += (bytes + 255) & ~(size_t)255;
    return p;
  };
  unsigned short* Xb    = (unsigned short*)alloc((size_t)T_TOK * HID * 2);
  unsigned short* WqkvT = (unsigned short*)alloc((size_t)3 * HID * HID * 2);
  unsigned short* WoT   = (unsigned short*)alloc((size_t)HID * HID * 2);
  unsigned short* Qh    = (unsigned short*)alloc((size_t)NH * T_TOK * HD * 2);
  unsigned short* Kh    = (unsigned short*)alloc((size_t)NH * T_TOK * HD * 2);
  unsigned short* Vt    = (unsigned short*)alloc((size_t)NH * HD * T_TOK * 2);
  unsigned short* Ob    = (unsigned short*)alloc((size_t)T_TOK * HID * 2);
  float*          ctab  = (float*)alloc((size_t)T_TOK * 32 * 4);
  float*          stab  = (float*)alloc((size_t)T_TOK * 32 * 4);
  float*          Mp    = (float*)alloc((size_t)KVSPLIT * T_TOK * NH * 4);
  float*          Lp    = (float*)alloc((size_t)KVSPLIT * T_TOK * NH * 4);
  // REGION: QKV (f32 T x 3H = 37.75MB) aliased with Opart (f32 KVSPLIT x T x HID = 50.3MB).
  // QKV is dead once rope_split + v_transpose complete, before flash_attn writes Op.
  float*          QKV   = (float*)alloc((size_t)KVSPLIT * T_TOK * HID * 4);
  float*          Op    = QKV;

  cvt_bf16<<<(T_TOK * HID / 4 + 255) / 256, 256, 0, stream>>>(X, Xb, T_TOK * HID);
  transpose_cvt<<<dim3(3 * HID / 32, HID / 32), 256, 0, stream>>>(Wqkv, WqkvT, HID, 3 * HID);
  transpose_cvt<<<dim3(HID / 32, HID / 32), 256, 0, stream>>>(Wo, WoT, HID, HID);
  rope_table<<<T_TOK * 32 / 256, 256, 0, stream>>>(pos, ctab, stab);

  gemm_bt<<<dim3(3 * HID / 128, T_TOK / 128), 256, 0, stream>>>(Xb, WqkvT, QKV, T_TOK, 3 * HID, HID);

  rope_split<<<T_TOK * NH * 32 / 256, 256, 0, stream>>>(QKV, ctab, stab, Qh, Kh);
  v_transpose<<<dim3(T_TOK / 64, NH), 256, 0, stream>>>(QKV, Vt);

  flash_attn<<<dim3((T_TOK / 64) * NH * KVSPLIT), 256, 0, stream>>>(Qh, Kh, Vt, mask, Op, Mp, Lp);
  combine<<<T_TOK, 256, 0, stream>>>(Op, Mp, Lp, Ob);

  gemm_bt<<<dim3(HID / 128, T_TOK / 128), 256, 0, stream>>>(Ob, WoT, out, T_TOK, HID, HID);
}

// Round 5
// 212.890 us; speedup vs baseline: 1.0298x; 1.0298x over previous
//
#include <hip/hip_runtime.h>
#include <hip/hip_bf16.h>
#include <math.h>

#define T_TOK 3072
#define HID   1024
#define NH    16
#define HD    64
#define KVSPLIT 4
#define KVCHUNK (T_TOK / KVSPLIT)   // 768
#define LOG2E 1.4426950408889634f

typedef __attribute__((ext_vector_type(8))) short bf16x8;
typedef __attribute__((ext_vector_type(4))) short bf16x4;
typedef __attribute__((ext_vector_type(4))) float f32x4;

static __device__ __forceinline__ unsigned short f2bf(float x) {
  __hip_bfloat16 h = __float2bfloat16(x);
  return __builtin_bit_cast(unsigned short, h);
}

// swizzled LDS short-index for a [rows][64 bf16] tile, row stride 128B.
// byte address = row*128 + (col_bytes ^ ((row&7)<<4)); identical on write & read.
static __device__ __forceinline__ int swz(int row, int cb) {
  return row * 64 + ((cb ^ ((row & 7) << 4)) >> 1);
}

// ---------------- elementwise fp32 -> bf16 ----------------
__global__ __launch_bounds__(256) void cvt_bf16(const float* __restrict__ in,
                                                unsigned short* __restrict__ out, int n) {
  int i = (blockIdx.x * 256 + threadIdx.x) * 4;
  if (i < n) {
    float4 v = *(const float4*)(in + i);
    ushort4 o;
    o.x = f2bf(v.x); o.y = f2bf(v.y); o.z = f2bf(v.z); o.w = f2bf(v.w);
    *(ushort4*)(out + i) = o;
  }
}

// ---------------- transpose + convert: out[C][R] = bf16(in[R][C]) ----------------
__global__ __launch_bounds__(256) void transpose_cvt(const float* __restrict__ in,
                                                     unsigned short* __restrict__ out,
                                                     int R, int C) {
  __shared__ float tile[32][33];
  int c0 = blockIdx.x * 32, r0 = blockIdx.y * 32;
  int tx = threadIdx.x & 31, ty = threadIdx.x >> 5; // ty 0..7
  #pragma unroll
  for (int i = 0; i < 32; i += 8)
    tile[ty + i][tx] = in[(size_t)(r0 + ty + i) * C + c0 + tx];
  __syncthreads();
  #pragma unroll
  for (int i = 0; i < 32; i += 8)
    out[(size_t)(c0 + ty + i) * R + r0 + tx] = f2bf(tile[tx][ty + i]);
}

// ---------------- RoPE cos/sin tables [T][32] ----------------
__global__ __launch_bounds__(256) void rope_table(const int* __restrict__ pos,
                                                  float* __restrict__ ctab,
                                                  float* __restrict__ stab) {
  int i = blockIdx.x * 256 + threadIdx.x;  // T*32
  int t = i >> 5, j = i & 31;
  float inv = expf(-(float)j * 0.28782313662425572f);  // 10000^(-j/32)
  float f = (float)pos[t] * inv;
  ctab[i] = cosf(f);
  stab[i] = sinf(f);
}

// ---------------- RoPE apply + split Q,K to [H][T][D] bf16 ----------------
// Q is pre-scaled by 0.125 * log2(e) so softmax runs in exp2 domain.
__global__ __launch_bounds__(256) void rope_split(const float* __restrict__ QKV,
                                                  const float* __restrict__ ctab,
                                                  const float* __restrict__ stab,
                                                  unsigned short* __restrict__ Qh,
                                                  unsigned short* __restrict__ Kh) {
  const float QSCL = 0.18033688011112042f;  // 0.125 * log2e
  int i = blockIdx.x * 256 + threadIdx.x;  // T*NH*32
  int j = i & 31, h = (i >> 5) & 15, t = i >> 9;
  size_t base = (size_t)t * (3 * HID) + h * HD + j;
  float c = ctab[t * 32 + j], s = stab[t * 32 + j];
  float q1 = QKV[base], q2 = QKV[base + 32];
  float k1 = QKV[base + HID], k2 = QKV[base + HID + 32];
  size_t ob = ((size_t)h * T_TOK + t) * HD + j;
  Qh[ob]      = f2bf((q1 * c - q2 * s) * QSCL);
  Qh[ob + 32] = f2bf((q2 * c + q1 * s) * QSCL);
  Kh[ob]      = f2bf(k1 * c - k2 * s);
  Kh[ob + 32] = f2bf(k2 * c + k1 * s);
}

// ---------------- V: QKV[:,2048+h*64+d] -> Vt[H][D][T] bf16 ----------------
__global__ __launch_bounds__(256) void v_transpose(const float* __restrict__ QKV,
                                                   unsigned short* __restrict__ Vt) {
  int h = blockIdx.y;
  int t0 = blockIdx.x * 64;
  __shared__ unsigned short lds[64][72];
  int tx = threadIdx.x & 63, ty = threadIdx.x >> 6;  // ty 0..3
  #pragma unroll
  for (int i = 0; i < 16; ++i) {
    int t = ty * 16 + i;
    lds[tx][t] = f2bf(QKV[(size_t)(t0 + t) * (3 * HID) + 2 * HID + h * HD + tx]);
  }
  __syncthreads();
  #pragma unroll
  for (int i = 0; i < 16; ++i) {
    int d = ty * 16 + i;
    Vt[((size_t)h * HD + d) * T_TOK + t0 + tx] = lds[d][tx];
  }
}

// ---------------- GEMM: C[M,N] f32 = A[M,K] bf16 x Bt[N,K] bf16 ----------------
__global__ __launch_bounds__(256) void gemm_bt(const unsigned short* __restrict__ A,
                                               const unsigned short* __restrict__ Bt,
                                               float* __restrict__ C,
                                               int M, int N, int K) {
  __shared__ unsigned short As[128 * 64];
  __shared__ unsigned short Bs[128 * 64];
  const int lane = threadIdx.x & 63;
  const int wv = threadIdx.x >> 6;
  const int wm = wv >> 1, wn = wv & 1;
  const int r = lane & 15, hi = lane >> 4;
  const int m0 = blockIdx.y * 128, n0 = blockIdx.x * 128;
  f32x4 acc[4][4] = {};
  for (int kt = 0; kt < K; kt += 64) {
    __syncthreads();
    #pragma unroll
    for (int i = 0; i < 4; ++i) {
      int o = (wv * 4 + i) * 1024 + lane * 16;  // byte offset into 16KB tile
      int row = o >> 7;                          // 128B per row (64 bf16)
      int col = (o & 127) >> 1;
      const unsigned short* ga = A + (size_t)(m0 + row) * K + kt + col;
      __builtin_amdgcn_global_load_lds(
          (const __attribute__((address_space(1))) unsigned int*)ga,
          (__attribute__((address_space(3))) unsigned int*)((char*)As + (wv * 4 + i) * 1024),
          16, 0, 0);
      const unsigned short* gb = Bt + (size_t)(n0 + row) * K + kt + col;
      __builtin_amdgcn_global_load_lds(
          (const __attribute__((address_space(1))) unsigned int*)gb,
          (__attribute__((address_space(3))) unsigned int*)((char*)Bs + (wv * 4 + i) * 1024),
          16, 0, 0);
    }
    __syncthreads();
    #pragma unroll
    for (int kk = 0; kk < 2; ++kk) {
      bf16x8 a[4], b[4];
      #pragma unroll
      for (int tm = 0; tm < 4; ++tm)
        a[tm] = *(const bf16x8*)&As[(wm * 64 + tm * 16 + r) * 64 + kk * 32 + hi * 8];
      #pragma unroll
      for (int tn = 0; tn < 4; ++tn)
        b[tn] = *(const bf16x8*)&Bs[(wn * 64 + tn * 16 + r) * 64 + kk * 32 + hi * 8];
      #pragma unroll
      for (int tm = 0; tm < 4; ++tm)
        #pragma unroll
        for (int tn = 0; tn < 4; ++tn)
          acc[tm][tn] = __builtin_amdgcn_mfma_f32_16x16x32_bf16(a[tm], b[tn], acc[tm][tn], 0, 0, 0);
    }
  }
  #pragma unroll
  for (int tm = 0; tm < 4; ++tm)
    #pragma unroll
    for (int tn = 0; tn < 4; ++tn) {
      int colg = n0 + wn * 64 + tn * 16 + r;
      int rowg = m0 + wm * 64 + tm * 16 + hi * 4;
      float* cp = C + (size_t)rowg * N + colg;
      #pragma unroll
      for (int j = 0; j < 4; ++j) cp[(size_t)j * N] = acc[tm][tn][j];
    }
}

// ---------------- flash attention, KV-split, 2 q-groups per wave ----------------
// grid: 1D (T/128) * NH * KVSPLIT, XCD-remapped. block 256 = 4 waves.
// Each wave owns 32 q-rows as TWO independent 16-row groups -> two independent
// dependency chains interleave (ILP hides softmax/shuffle/MFMA latency), and
// K/V LDS fragments are read once and feed both groups' MFMAs.
// Sync structure identical to R2 single-buffer (best known).
__global__ __launch_bounds__(256) void flash_attn(const unsigned short* __restrict__ Qh,
                                                  const unsigned short* __restrict__ Kh,
                                                  const unsigned short* __restrict__ Vt,
                                                  const float* __restrict__ mask,
                                                  float* __restrict__ Op,
                                                  float* __restrict__ Mp,
                                                  float* __restrict__ Lp) {
  const int NBLK = (T_TOK / 128) * NH * KVSPLIT;    // 1536, divisible by 8
  int id = blockIdx.x;
  int sid = (id & 7) * (NBLK / 8) + (id >> 3);      // bijective XCD chunking
  const int h = sid & 15;
  int t2 = sid >> 4;                                 // 0..95
  const int qx = t2 % (T_TOK / 128);
  const int z  = t2 / (T_TOK / 128);
  const int q0 = qx * 128;
  const int kv0 = z * KVCHUNK;

  __shared__ unsigned short Ks[64 * 64];
  __shared__ unsigned short Vs[64 * 64];
  const int lane = threadIdx.x & 63, wv = threadIdx.x >> 6;
  const int r = lane & 15, hi = lane >> 4;
  // two q-groups per wave
  const int qrow0 = q0 + wv * 32 + r;
  const int qrow1 = qrow0 + 16;
  bf16x8 qf[2][2];
  qf[0][0] = *(const bf16x8*)(Qh + ((size_t)h * T_TOK + qrow0) * HD + hi * 8);
  qf[0][1] = *(const bf16x8*)(Qh + ((size_t)h * T_TOK + qrow0) * HD + 32 + hi * 8);
  qf[1][0] = *(const bf16x8*)(Qh + ((size_t)h * T_TOK + qrow1) * HD + hi * 8);
  qf[1][1] = *(const bf16x8*)(Qh + ((size_t)h * T_TOK + qrow1) * HD + 32 + hi * 8);
  f32x4 acc_o[2][4] = {};
  float m2[2] = {-INFINITY, -INFINITY};
  float l2[2] = {0.f, 0.f};

  // global_load_lds staging: LDS written linearly (base + lane*16), source
  // pre-swizzled so LDS[row][cb] = src[row][cb ^ ((row&7)<<4)].
  const int ldrow = lane >> 3;                         // == dest row & 7
  const int colS  = ((lane & 7) * 16) ^ (ldrow << 4);  // source byte col
  const unsigned short* kga = Kh + ((size_t)h * T_TOK + wv * 16 + ldrow) * HD + (colS >> 1);
  const unsigned short* vga = Vt + ((size_t)h * HD + wv * 16 + ldrow) * T_TOK + (colS >> 1);
  char* ksd = (char*)Ks + wv * 2048;
  char* vsd = (char*)Vs + wv * 2048;
  const float* mrow0 = mask + (size_t)qrow0 * T_TOK;
  const float* mrow1 = mask + (size_t)qrow1 * T_TOK;

  for (int s0 = kv0; s0 < kv0 + KVCHUNK; s0 += 64) {
    __syncthreads();  // previous tile's LDS reads complete
    __builtin_amdgcn_global_load_lds(
        (const __attribute__((address_space(1))) unsigned int*)(kga + (size_t)s0 * HD),
        (__attribute__((address_space(3))) unsigned int*)ksd, 16, 0, 0);
    __builtin_amdgcn_global_load_lds(
        (const __attribute__((address_space(1))) unsigned int*)(kga + (size_t)s0 * HD + 8 * HD),
        (__attribute__((address_space(3))) unsigned int*)(ksd + 1024), 16, 0, 0);
    __builtin_amdgcn_global_load_lds(
        (const __attribute__((address_space(1))) unsigned int*)(vga + s0),
        (__attribute__((address_space(3))) unsigned int*)vsd, 16, 0, 0);
    __builtin_amdgcn_global_load_lds(
        (const __attribute__((address_space(1))) unsigned int*)(vga + s0 + 8 * T_TOK),
        (__attribute__((address_space(3))) unsigned int*)(vsd + 1024), 16, 0, 0);
    // mask loads issue here; latency hides under the staging drain
    float4 mk[2][4];
    #pragma unroll
    for (int b = 0; b < 4; ++b) {
      mk[0][b] = *(const float4*)(mrow0 + s0 + b * 16 + hi * 4);
      mk[1][b] = *(const float4*)(mrow1 + s0 + b * 16 + hi * 4);
    }
    __syncthreads();  // vmcnt(0) drain -> LDS + mask ready

    // QK^T -> S^T[kv,q] for both q-groups; K fragments read once
    float sv[2][16];
    __builtin_amdgcn_s_setprio(1);
    #pragma unroll
    for (int b = 0; b < 4; ++b) {
      bf16x8 kf0 = *(const bf16x8*)&Ks[swz(b * 16 + r, hi * 16)];
      bf16x8 kf1 = *(const bf16x8*)&Ks[swz(b * 16 + r, 64 + hi * 16)];
      #pragma unroll
      for (int g = 0; g < 2; ++g) {
        f32x4 zf = {};
        zf = __builtin_amdgcn_mfma_f32_16x16x32_bf16(kf0, qf[g][0], zf, 0, 0, 0);
        zf = __builtin_amdgcn_mfma_f32_16x16x32_bf16(kf1, qf[g][1], zf, 0, 0, 0);
        sv[g][b * 4 + 0] = fmaf(mk[g][b].x, LOG2E, zf[0]);
        sv[g][b * 4 + 1] = fmaf(mk[g][b].y, LOG2E, zf[1]);
        sv[g][b * 4 + 2] = fmaf(mk[g][b].z, LOG2E, zf[2]);
        sv[g][b * 4 + 3] = fmaf(mk[g][b].w, LOG2E, zf[3]);
      }
    }
    __builtin_amdgcn_s_setprio(0);

    // online softmax per group (independent chains -> ILP)
    bf16x4 pa[2][4];
    float ps[2];
    #pragma unroll
    for (int g = 0; g < 2; ++g) {
      float t0 = fmaxf(fmaxf(sv[g][0], sv[g][1]), sv[g][2]);
      float t1 = fmaxf(fmaxf(sv[g][3], sv[g][4]), sv[g][5]);
      float t2m = fmaxf(fmaxf(sv[g][6], sv[g][7]), sv[g][8]);
      float t3 = fmaxf(fmaxf(sv[g][9], sv[g][10]), sv[g][11]);
      float t4 = fmaxf(fmaxf(sv[g][12], sv[g][13]), sv[g][14]);
      float pmax = fmaxf(fmaxf(fmaxf(t0, t1), t2m), fmaxf(fmaxf(t3, t4), sv[g][15]));
      pmax = fmaxf(pmax, __shfl_xor(pmax, 16));
      pmax = fmaxf(pmax, __shfl_xor(pmax, 32));

      // defer-max: only rescale when the running max grew by > 8 (log2 units)
      if (__any(pmax > m2[g] + 8.f)) {
        float mnew = fmaxf(m2[g], pmax);
        float sc = __builtin_amdgcn_exp2f(m2[g] - mnew);
        m2[g] = mnew;
        l2[g] *= sc;
        float sc0 = __shfl(sc, hi * 4 + 0);
        float sc1 = __shfl(sc, hi * 4 + 1);
        float sc2 = __shfl(sc, hi * 4 + 2);
        float sc3 = __shfl(sc, hi * 4 + 3);
        #pragma unroll
        for (int d = 0; d < 4; ++d) {
          acc_o[g][d][0] *= sc0; acc_o[g][d][1] *= sc1;
          acc_o[g][d][2] *= sc2; acc_o[g][d][3] *= sc3;
        }
      }

      // P = exp2(sv - m), packed straight into K=16 A-fragments
      float pss = 0.f;
      #pragma unroll
      for (int b = 0; b < 4; ++b) {
        bf16x4 t;
        #pragma unroll
        for (int j = 0; j < 4; ++j) {
          float p = __builtin_amdgcn_exp2f(sv[g][b * 4 + j] - m2[g]);
          pss += p;
          t[j] = (short)f2bf(p);
        }
        pa[g][b] = t;
      }
      ps[g] = pss;
    }

    // PV: O[q,d] += P[q,kv] * V[kv,d]; V fragments read once for both groups
    __builtin_amdgcn_s_setprio(1);
    #pragma unroll
    for (int d = 0; d < 4; ++d)
      #pragma unroll
      for (int b = 0; b < 4; ++b) {
        bf16x4 vf = *(const bf16x4*)&Vs[swz(d * 16 + r, b * 32 + hi * 8)];
        acc_o[0][d] = __builtin_amdgcn_mfma_f32_16x16x16bf16_1k(pa[0][b], vf, acc_o[0][d], 0, 0, 0);
        acc_o[1][d] = __builtin_amdgcn_mfma_f32_16x16x16bf16_1k(pa[1][b], vf, acc_o[1][d], 0, 0, 0);
      }
    __builtin_amdgcn_s_setprio(0);

    // l-updates (shuffle latency hides under PV MFMAs above)
    #pragma unroll
    for (int g = 0; g < 2; ++g) {
      float pss = ps[g];
      pss += __shfl_xor(pss, 16);
      pss += __shfl_xor(pss, 32);
      l2[g] += pss;
    }
  }

  // epilogue: write unnormalized partials + (m,l) (m in log2 domain)
  #pragma unroll
  for (int g = 0; g < 2; ++g)
    #pragma unroll
    for (int d = 0; d < 4; ++d)
      #pragma unroll
      for (int j = 0; j < 4; ++j) {
        int trow = q0 + wv * 32 + g * 16 + hi * 4 + j;
        Op[(((size_t)z * T_TOK + trow) * NH + h) * HD + d * 16 + r] = acc_o[g][d][j];
      }
  if (hi == 0) {
    size_t mi0 = ((size_t)z * T_TOK + qrow0) * NH + h;
    size_t mi1 = ((size_t)z * T_TOK + qrow1) * NH + h;
    Mp[mi0] = m2[0];
    Lp[mi0] = l2[0];
    Mp[mi1] = m2[1];
    Lp[mi1] = l2[1];
  }
}

// ---------------- combine KV-split partials (log2-domain maxes) ----------------
__global__ __launch_bounds__(256) void combine(const float* __restrict__ Op,
                                               const float* __restrict__ Mp,
                                               const float* __restrict__ Lp,
                                               unsigned short* __restrict__ Ob) {
  int idx = blockIdx.x * 256 + threadIdx.x;  // T*256 total (4 floats each)
  int t = idx >> 8;
  int q4 = (idx & 255) * 4;  // within [HID): h*64 + d
  int h = q4 >> 6, d = q4 & 63;
  float mz[KVSPLIT], lz[KVSPLIT];
  float ms = -INFINITY;
  #pragma unroll
  for (int zz = 0; zz < KVSPLIT; ++zz) {
    size_t mi = ((size_t)zz * T_TOK + t) * NH + h;
    mz[zz] = Mp[mi];
    lz[zz] = Lp[mi];
    ms = fmaxf(ms, mz[zz]);
  }
  float lsum = 0.f;
  float w[KVSPLIT];
  #pragma unroll
  for (int zz = 0; zz < KVSPLIT; ++zz) {
    w[zz] = __builtin_amdgcn_exp2f(mz[zz] - ms);
    lsum += lz[zz] * w[zz];
  }
  float4 o = {0.f, 0.f, 0.f, 0.f};
  #pragma unroll
  for (int zz = 0; zz < KVSPLIT; ++zz) {
    float4 p = *(const float4*)(Op + (((size_t)zz * T_TOK + t) * NH + h) * HD + d);
    o.x += p.x * w[zz]; o.y += p.y * w[zz];
    o.z += p.z * w[zz]; o.w += p.w * w[zz];
  }
  float inv = 1.f / lsum;
  ushort4 ob;
  ob.x = f2bf(o.x * inv); ob.y = f2bf(o.y * inv);
  ob.z = f2bf(o.z * inv); ob.w = f2bf(o.w * inv);
  *(ushort4*)(Ob + (size_t)t * HID + q4) = ob;
}

extern "C" void kernel_launch(void* const* d_in, const int* in_sizes, int n_in,
                              void* d_out, int out_size, void* d_ws, size_t ws_size,
                              hipStream_t stream) {
  const float* X    = (const float*)d_in[0];
  const float* Wqkv = (const float*)d_in[1];
  const float* Wo   = (const float*)d_in[2];
  const float* mask = (const float*)d_in[3];
  const int*   pos  = (const int*)d_in[4];
  float* out = (float*)d_out;

  char* ws = (char*)d_ws;
  size_t off = 0;
  auto alloc = [&](size_t bytes) {
    char* p = ws + off;
    off += (bytes + 255) & ~(size_t)255;
    return p;
  };
  unsigned short* Xb    = (unsigned short*)alloc((size_t)T_TOK * HID * 2);
  unsigned short* WqkvT = (unsigned short*)alloc((size_t)3 * HID * HID * 2);
  unsigned short* WoT   = (unsigned short*)alloc((size_t)HID * HID * 2);
  unsigned short* Qh    = (unsigned short*)alloc((size_t)NH * T_TOK * HD * 2);
  unsigned short* Kh    = (unsigned short*)alloc((size_t)NH * T_TOK * HD * 2);
  unsigned short* Vt    = (unsigned short*)alloc((size_t)NH * HD * T_TOK * 2);
  unsigned short* Ob    = (unsigned short*)alloc((size_t)T_TOK * HID * 2);
  float*          ctab  = (float*)alloc((size_t)T_TOK * 32 * 4);
  float*          stab  = (float*)alloc((size_t)T_TOK * 32 * 4);
  float*          Mp    = (float*)alloc((size_t)KVSPLIT * T_TOK * NH * 4);
  float*          Lp    = (float*)alloc((size_t)KVSPLIT * T_TOK * NH * 4);
  // REGION: QKV (f32 T x 3H = 37.75MB) aliased with Opart (f32 KVSPLIT x T x HID = 50.3MB).
  // QKV is dead once rope_split + v_transpose complete, before flash_attn writes Op.
  float*          QKV   = (float*)alloc((size_t)KVSPLIT * T_TOK * HID * 4);
  float*          Op    = QKV;

  cvt_bf16<<<(T_TOK * HID / 4 + 255) / 256, 256, 0, stream>>>(X, Xb, T_TOK * HID);
  transpose_cvt<<<dim3(3 * HID / 32, HID / 32), 256, 0, stream>>>(Wqkv, WqkvT, HID, 3 * HID);
  transpose_cvt<<<dim3(HID / 32, HID / 32), 256, 0, stream>>>(Wo, WoT, HID, HID);
  rope_table<<<T_TOK * 32 / 256, 256, 0, stream>>>(pos, ctab, stab);

  gemm_bt<<<dim3(3 * HID / 128, T_TOK / 128), 256, 0, stream>>>(Xb, WqkvT, QKV, T_TOK, 3 * HID, HID);

  rope_split<<<T_TOK * NH * 32 / 256, 256, 0, stream>>>(QKV, ctab, stab, Qh, Kh);
  v_transpose<<<dim3(T_TOK / 64, NH), 256, 0, stream>>>(QKV, Vt);

  flash_attn<<<dim3((T_TOK / 128) * NH * KVSPLIT), 256, 0, stream>>>(Qh, Kh, Vt, mask, Op, Mp, Lp);
  combine<<<T_TOK, 256, 0, stream>>>(Op, Mp, Lp, Ob);

  gemm_bt<<<dim3(HID / 128, T_TOK / 128), 256, 0, stream>>>(Ob, WoT, out, T_TOK, HID, HID);
}